// Round 1
// 816.913 us; speedup vs baseline: 1.2911x; 1.2911x over previous
//
#include <hip/hip_runtime.h>

#define ND 6000
#define NT 6000
#define NPOS 100000
#define NLINK 200000
#define KPAD 6016

typedef unsigned short u16;
typedef __attribute__((ext_vector_type(8))) short s16x8;
typedef __attribute__((ext_vector_type(4))) float f32x4;

__device__ __forceinline__ u16 f2bf(float f){
  union { float f; unsigned u; } c; c.f = f;
  return (u16)((c.u + 0x7FFFu + ((c.u >> 16) & 1u)) >> 16);
}

// ---- fused row + col sums of R (f32), atomic partials ----
// float4 loads (1KB/wave/trip), 6x200 grid (4.7 waves/SIMD), 30-row stripes
// (24 same-address row atomics instead of 96).
__global__ __launch_bounds__(256) void rc_sums_k(const float* __restrict__ R,
                                                 float* __restrict__ rsum, float* __restrict__ csum){
  const int c4 = blockIdx.x * 256 + threadIdx.x;   // float4 column index
  const bool act = c4 < NT / 4;
  const int r0 = blockIdx.y * 30;
  const float* __restrict__ base = R + (long)r0 * NT + (long)c4 * 4;
  float cx = 0.f, cy = 0.f, cz = 0.f, cw = 0.f;
  #pragma unroll 6
  for (int r = 0; r < 30; ++r){
    float4 v = {0.f, 0.f, 0.f, 0.f};
    if (act) v = *(const float4*)(base + (long)r * NT);
    cx += v.x; cy += v.y; cz += v.z; cw += v.w;
    float s = (v.x + v.y) + (v.z + v.w);
    #pragma unroll
    for (int o = 32; o > 0; o >>= 1) s += __shfl_down(s, o, 64);
    if ((threadIdx.x & 63) == 0) atomicAdd(&rsum[r0 + r], s);
  }
  if (act){
    float* cp = csum + (long)c4 * 4;
    atomicAdd(cp + 0, cx); atomicAdd(cp + 1, cy);
    atomicAdd(cp + 2, cz); atomicAdd(cp + 3, cw);
  }
}

// ---- row sums of D and T -> inv-sqrt degree directly ----
__global__ __launch_bounds__(256) void rowinv2_k(const float* __restrict__ D, const float* __restrict__ T,
                                                 float* __restrict__ dd, float* __restrict__ tt){
  const float* A = blockIdx.y ? T : D;
  float* out = blockIdx.y ? tt : dd;
  long row = blockIdx.x;
  const float* p = A + row * ND;
  float s = 0.f;
  for (int c = threadIdx.x * 4; c < ND; c += 1024){
    float4 v = *(const float4*)(p + c);
    s += v.x + v.y + v.z + v.w;
  }
  #pragma unroll
  for (int o = 32; o > 0; o >>= 1) s += __shfl_down(s, o, 64);
  __shared__ float ws[4];
  if ((threadIdx.x & 63) == 0) ws[threadIdx.x >> 6] = s;
  __syncthreads();
  if (threadIdx.x == 0){
    float t = ws[0] + ws[1] + ws[2] + ws[3];
    out[row] = rsqrtf(t == 0.f ? 1.f : t);
  }
}

__global__ __launch_bounds__(256) void invsqrt2_k(const float* __restrict__ rsum, const float* __restrict__ csum,
                                                  float* __restrict__ dt, float* __restrict__ td){
  int i = blockIdx.x * 256 + threadIdx.x;
  if (i < ND){ float v = rsum[i]; dt[i] = rsqrtf(v == 0.f ? 1.f : v); }
  else if (i < ND + NT){ float v = csum[i - ND]; td[i - ND] = rsqrtf(v == 0.f ? 1.f : v); }
}

// ---- link histogram ----
__global__ __launch_bounds__(256) void hist_k(const int* __restrict__ PI, const int* __restrict__ NI,
                                              int* __restrict__ hd, int* __restrict__ ht){
  int id = blockIdx.x * 256 + threadIdx.x;
  if (id >= NLINK) return;
  const int* ip = (id < NPOS) ? (PI + 2 * (long)id) : (NI + 2 * (long)(id - NPOS));
  atomicAdd(&hd[ip[0]], 1);
  atomicAdd(&ht[ip[1]], 1);
}

// ---- exclusive scan of both histograms (single block) ----
__global__ __launch_bounds__(256) void scan_k(const int* __restrict__ h0, const int* __restrict__ h1,
                                              int* __restrict__ o0, int* __restrict__ o1,
                                              int* __restrict__ c0, int* __restrict__ c1){
  __shared__ int sh[256];
  for (int m = 0; m < 2; ++m){
    const int* h = m ? h1 : h0;
    int* o = m ? o1 : o0;
    int* cu = m ? c1 : c0;
    int base = threadIdx.x * 24;
    int loc[24]; int s = 0;
    #pragma unroll
    for (int r = 0; r < 24; ++r){
      loc[r] = s;
      int idx = base + r;
      s += (idx < ND) ? h[idx] : 0;
    }
    sh[threadIdx.x] = s;
    __syncthreads();
    int v = s;
    for (int d = 1; d < 256; d <<= 1){
      int t = (threadIdx.x >= d) ? sh[threadIdx.x - d] : 0;
      __syncthreads();
      v += t; sh[threadIdx.x] = v;
      __syncthreads();
    }
    int prefix = v - s;   // exclusive prefix of this thread's chunk
    #pragma unroll
    for (int r = 0; r < 24; ++r){
      int idx = base + r;
      if (idx < ND){ o[idx] = prefix + loc[r]; cu[idx] = prefix + loc[r]; }
    }
    __syncthreads();
  }
}

// ---- fill CSR buckets: coef = sigmoid(profile . W_pro) * dt_i * td_j * R[i][j] ----
__global__ __launch_bounds__(256) void fill_k(const int* __restrict__ PI, const int* __restrict__ NI,
    const float* __restrict__ PP, const float* __restrict__ NP, const float* __restrict__ WP,
    const float* __restrict__ dt, const float* __restrict__ td, const float* __restrict__ R,
    int* __restrict__ cur_d, int* __restrict__ cur_t,
    int* __restrict__ jd, float* __restrict__ cd, int* __restrict__ jt, float* __restrict__ ct){
  int id = blockIdx.x * 256 + threadIdx.x;
  if (id >= NLINK) return;
  const int* ip = (id < NPOS) ? (PI + 2 * (long)id) : (NI + 2 * (long)(id - NPOS));
  int i = ip[0], j = ip[1];
  const float* p = (id < NPOS) ? (PP + 16 * (long)id) : (NP + 16 * (long)(id - NPOS));
  float s = 0.f;
  #pragma unroll
  for (int q = 0; q < 4; ++q){
    float4 a = *(const float4*)(p + 4 * q);
    float4 w = *(const float4*)(WP + 4 * q);
    s += a.x * w.x + a.y * w.y + a.z * w.z + a.w * w.w;
  }
  float sig = 1.f / (1.f + __expf(-s));
  float coef = sig * dt[i] * td[j] * R[(long)i * NT + j];
  int ed = atomicAdd(&cur_d[i], 1); jd[ed] = j; cd[ed] = coef;
  int et = atomicAdd(&cur_t[j], 1); jt[et] = i; ct[et] = coef;
}

// ---- gather: one wave per destination row, 2 feats/lane, write relu'd f32 ----
__global__ __launch_bounds__(256) void gather_k(
    const int* __restrict__ off_d, const int* __restrict__ h_d, const int* __restrict__ jd,
    const float* __restrict__ cd, const float* __restrict__ Ht, float* __restrict__ accdt,
    const int* __restrict__ off_t, const int* __restrict__ h_t, const int* __restrict__ jt,
    const float* __restrict__ ct, const float* __restrict__ Hd, float* __restrict__ acctd){
  const int* off = blockIdx.y ? off_t : off_d;
  const int* hh  = blockIdx.y ? h_t  : h_d;
  const int* js  = blockIdx.y ? jt   : jd;
  const float* cs= blockIdx.y ? ct   : cd;
  const float* H = blockIdx.y ? Hd   : Ht;
  float* acc     = blockIdx.y ? acctd : accdt;
  int row = blockIdx.x * 4 + (threadIdx.x >> 6);
  int lane = threadIdx.x & 63, f = lane * 2;
  int e0 = off[row], n = hh[row];
  float ax = 0.f, ay = 0.f;
  for (int e = e0; e < e0 + n; ++e){
    int j = js[e]; float c = cs[e];
    const float* hp = H + (long)j * 128 + f;
    ax += c * hp[0]; ay += c * hp[1];
  }
  float* out = acc + (long)row * 128 + f;
  out[0] = fmaxf(ax, 0.f); out[1] = fmaxf(ay, 0.f);
}

// ---- Bt[n][k] = bf16(scale[k] * H[k][n]), zero-padded to Kpad ----
__global__ __launch_bounds__(256) void transpose_scale_k(const float* __restrict__ H,
    const float* __restrict__ scale, u16* __restrict__ Bt, int K, int Kpad){
  __shared__ u16 tile[32][33];
  int k0 = blockIdx.x * 32, n0 = blockIdx.y * 32;
  int tr = threadIdx.x >> 5, tc = threadIdx.x & 31;
  #pragma unroll
  for (int i = 0; i < 4; ++i){
    int k = k0 + tr + i * 8;
    float v = 0.f;
    if (k < K){
      v = H[(long)k * 128 + n0 + tc];
      if (scale) v *= scale[k];
    }
    tile[tr + i * 8][tc] = f2bf(v);
  }
  __syncthreads();
  #pragma unroll
  for (int i = 0; i < 4; ++i){
    int n = n0 + tr + i * 8;
    int k = k0 + tc;
    Bt[(long)n * Kpad + k] = tile[tc][tr + i * 8];
  }
}

// ---- GEMM (plain f32 A): C[Mx128] = relu(rs_i * (A @ B)), Bt bf16 [128][Kpad] ----
__global__ __launch_bounds__(256) void gemm_plain_k(
    const float* __restrict__ A0, const float* __restrict__ A1,
    const u16* __restrict__ B0, const u16* __restrict__ B1,
    const float* __restrict__ r0p, const float* __restrict__ r1p,
    float* __restrict__ C0, float* __restrict__ C1,
    int M, int K, int Kpad){
  const float* A  = blockIdx.y ? A1 : A0;
  const u16* Bt   = blockIdx.y ? B1 : B0;
  const float* rs = blockIdx.y ? r1p : r0p;
  float* C        = blockIdx.y ? C1 : C0;

  __shared__ __align__(16) u16 Bs[128][40];
  const int tid = threadIdx.x;
  const int wave = tid >> 6, lane = tid & 63;
  const int quad = lane >> 4, l16 = lane & 15;
  const int row0 = blockIdx.x * 64 + wave * 16;
  const int arow = row0 + l16;

  f32x4 acc[8] = {};

  for (int k0 = 0; k0 < K; k0 += 32){
    for (int c = tid; c < 512; c += 256){
      int n = c >> 2, q = c & 3;
      *(uint4*)&Bs[n][q * 8] = *(const uint4*)(Bt + (long)n * Kpad + k0 + q * 8);
    }
    __syncthreads();

    int ka = k0 + quad * 8;
    s16x8 af = {};
    if (arow < M && ka < K){
      const float* ap = A + (long)arow * (long)K + ka;
      float4 a0 = *(const float4*)ap, a1 = *(const float4*)(ap + 4);
      af[0] = (short)f2bf(a0.x); af[1] = (short)f2bf(a0.y);
      af[2] = (short)f2bf(a0.z); af[3] = (short)f2bf(a0.w);
      af[4] = (short)f2bf(a1.x); af[5] = (short)f2bf(a1.y);
      af[6] = (short)f2bf(a1.z); af[7] = (short)f2bf(a1.w);
    }
    #pragma unroll
    for (int t = 0; t < 8; ++t){
      s16x8 bf = *(const s16x8*)&Bs[t * 16 + l16][quad * 8];
      acc[t] = __builtin_amdgcn_mfma_f32_16x16x32_bf16(af, bf, acc[t], 0, 0, 0);
    }
    __syncthreads();
  }

  #pragma unroll
  for (int t = 0; t < 8; ++t){
    #pragma unroll
    for (int r = 0; r < 4; ++r){
      int row = row0 + quad * 4 + r;
      if (row < M){
        float v = acc[t][r];
        if (rs) v *= rs[row];
        C[(long)row * 128 + t * 16 + l16] = fmaxf(v, 0.f);
      }
    }
  }
}

// ---- GEMM (concat A = [Xa | Xb | Xc], each Mx128 f32): C = relu(A @ B), K=384 ----
__global__ __launch_bounds__(256) void gemm_cat_k(
    const float* __restrict__ Xa0, const float* __restrict__ Xb0, const float* __restrict__ Xc0,
    const float* __restrict__ Xa1, const float* __restrict__ Xb1, const float* __restrict__ Xc1,
    const u16* __restrict__ B0, const u16* __restrict__ B1,
    float* __restrict__ C0, float* __restrict__ C1, int M){
  const float* Xa = blockIdx.y ? Xa1 : Xa0;
  const float* Xb = blockIdx.y ? Xb1 : Xb0;
  const float* Xc = blockIdx.y ? Xc1 : Xc0;
  const u16* Bt   = blockIdx.y ? B1 : B0;
  float* C        = blockIdx.y ? C1 : C0;

  __shared__ __align__(16) u16 Bs[128][40];
  const int tid = threadIdx.x;
  const int wave = tid >> 6, lane = tid & 63;
  const int quad = lane >> 4, l16 = lane & 15;
  const int row0 = blockIdx.x * 64 + wave * 16;
  const int arow = row0 + l16;

  f32x4 acc[8] = {};

  for (int k0 = 0; k0 < 384; k0 += 32){
    for (int c = tid; c < 512; c += 256){
      int n = c >> 2, q = c & 3;
      *(uint4*)&Bs[n][q * 8] = *(const uint4*)(Bt + (long)n * 384 + k0 + q * 8);
    }
    __syncthreads();

    int ka = k0 + quad * 8;
    int seg = ka >> 7, kk = ka & 127;
    const float* base = (seg == 0) ? Xa : ((seg == 1) ? Xb : Xc);
    s16x8 af = {};
    if (arow < M){
      const float* ap = base + (long)arow * 128 + kk;
      float4 a0 = *(const float4*)ap, a1 = *(const float4*)(ap + 4);
      af[0] = (short)f2bf(a0.x); af[1] = (short)f2bf(a0.y);
      af[2] = (short)f2bf(a0.z); af[3] = (short)f2bf(a0.w);
      af[4] = (short)f2bf(a1.x); af[5] = (short)f2bf(a1.y);
      af[6] = (short)f2bf(a1.z); af[7] = (short)f2bf(a1.w);
    }
    #pragma unroll
    for (int t = 0; t < 8; ++t){
      s16x8 bf = *(const s16x8*)&Bs[t * 16 + l16][quad * 8];
      acc[t] = __builtin_amdgcn_mfma_f32_16x16x32_bf16(af, bf, acc[t], 0, 0, 0);
    }
    __syncthreads();
  }

  #pragma unroll
  for (int t = 0; t < 8; ++t){
    #pragma unroll
    for (int r = 0; r < 4; ++r){
      int row = row0 + quad * 4 + r;
      if (row < M)
        C[(long)row * 128 + t * 16 + l16] = fmaxf(acc[t][r], 0.f);
    }
  }
}

extern "C" void kernel_launch(void* const* d_in, const int* in_sizes, int n_in,
                              void* d_out, int out_size, void* d_ws, size_t ws_size,
                              hipStream_t stream){
  const float* R  = (const float*)d_in[0];
  const float* D  = (const float*)d_in[1];
  const float* T  = (const float*)d_in[2];
  const float* Hd = (const float*)d_in[3];
  const float* Ht = (const float*)d_in[4];
  const float* PP = (const float*)d_in[5];
  const float* NP = (const float*)d_in[6];
  const int*   PI = (const int*)d_in[7];
  const int*   NI = (const int*)d_in[8];
  const float* WP = (const float*)d_in[9];
  const float* WD = (const float*)d_in[10];
  const float* WT = (const float*)d_in[11];

  char* ws = (char*)d_ws;
  float* rsum  = (float*)(ws + 0);
  float* csum  = (float*)(ws + 24000);
  int* hist_d  = (int*)(ws + 48000);
  int* hist_t  = (int*)(ws + 72000);
  int* off_d   = (int*)(ws + 96000);
  int* off_t   = (int*)(ws + 120000);
  int* cur_d   = (int*)(ws + 144000);
  int* cur_t   = (int*)(ws + 168000);
  float* dt    = (float*)(ws + 192000);
  float* td    = (float*)(ws + 216000);
  float* dd    = (float*)(ws + 240000);
  float* tt    = (float*)(ws + 264000);
  int*   jd    = (int*)(ws + 288000);
  float* cd    = (float*)(ws + 1088000);
  int*   jt    = (int*)(ws + 1888000);
  float* ct    = (float*)(ws + 2688000);
  float* accdt = (float*)(ws + 3488000);
  float* acctd = (float*)(ws + 6560000);
  float* Hdd   = (float*)(ws + 9632000);
  float* Htt   = (float*)(ws + 12704000);
  u16*   Btd   = (u16*)(ws + 15776000);
  u16*   Btt   = (u16*)(ws + 17316096);
  u16*   Wtd   = (u16*)(ws + 18856192);
  u16*   Wtt   = (u16*)(ws + 18954496);
  // total 19052800 bytes

  float* outd = (float*)d_out;
  float* outt = outd + (long)ND * 128;

  hipMemsetAsync(d_ws, 0, 96000, stream);   // rsum, csum, hist_d, hist_t

  rc_sums_k<<<dim3(6, 200), 256, 0, stream>>>(R, rsum, csum);
  rowinv2_k<<<dim3(ND, 2), 256, 0, stream>>>(D, T, dd, tt);
  invsqrt2_k<<<47, 256, 0, stream>>>(rsum, csum, dt, td);

  hist_k<<<782, 256, 0, stream>>>(PI, NI, hist_d, hist_t);
  scan_k<<<1, 256, 0, stream>>>(hist_d, hist_t, off_d, off_t, cur_d, cur_t);
  fill_k<<<782, 256, 0, stream>>>(PI, NI, PP, NP, WP, dt, td, R, cur_d, cur_t, jd, cd, jt, ct);
  gather_k<<<dim3(1500, 2), 256, 0, stream>>>(off_d, hist_d, jd, cd, Ht, accdt,
                                              off_t, hist_t, jt, ct, Hd, acctd);

  transpose_scale_k<<<dim3(188, 4), 256, 0, stream>>>(Hd, dd, Btd, ND, KPAD);
  transpose_scale_k<<<dim3(188, 4), 256, 0, stream>>>(Ht, tt, Btt, NT, KPAD);
  transpose_scale_k<<<dim3(12, 4), 256, 0, stream>>>(WD, nullptr, Wtd, 384, 384);
  transpose_scale_k<<<dim3(12, 4), 256, 0, stream>>>(WT, nullptr, Wtt, 384, 384);

  gemm_plain_k<<<dim3(94, 2), 256, 0, stream>>>(D, T, Btd, Btt, dd, tt, Hdd, Htt, ND, ND, KPAD);
  gemm_cat_k<<<dim3(94, 2), 256, 0, stream>>>(Hd, accdt, Hdd, Ht, acctd, Htt,
                                              Wtd, Wtt, outd, outt, ND);
}

// Round 3
// 672.206 us; speedup vs baseline: 1.5690x; 1.2153x over previous
//
#include <hip/hip_runtime.h>

#define ND 6000
#define NT 6000
#define NPOS 100000
#define NLINK 200000
#define KPAD 6016

typedef unsigned short u16;
typedef __attribute__((ext_vector_type(8))) short s16x8;
typedef __attribute__((ext_vector_type(4))) float f32x4;

__device__ __forceinline__ u16 f2bf(float f){
  union { float f; unsigned u; } c; c.f = f;
  return (u16)((c.u + 0x7FFFu + ((c.u >> 16) & 1u)) >> 16);
}

// ---- fused row + col sums of R (f32), atomic partials ----
__global__ __launch_bounds__(256) void rc_sums_k(const float* __restrict__ R,
                                                 float* __restrict__ rsum, float* __restrict__ csum){
  const int c4 = blockIdx.x * 256 + threadIdx.x;   // float4 column index
  const bool act = c4 < NT / 4;
  const int r0 = blockIdx.y * 30;
  const float* __restrict__ base = R + (long)r0 * NT + (long)c4 * 4;
  float cx = 0.f, cy = 0.f, cz = 0.f, cw = 0.f;
  #pragma unroll 6
  for (int r = 0; r < 30; ++r){
    float4 v = {0.f, 0.f, 0.f, 0.f};
    if (act) v = *(const float4*)(base + (long)r * NT);
    cx += v.x; cy += v.y; cz += v.z; cw += v.w;
    float s = (v.x + v.y) + (v.z + v.w);
    #pragma unroll
    for (int o = 32; o > 0; o >>= 1) s += __shfl_down(s, o, 64);
    if ((threadIdx.x & 63) == 0) atomicAdd(&rsum[r0 + r], s);
  }
  if (act){
    float* cp = csum + (long)c4 * 4;
    atomicAdd(cp + 0, cx); atomicAdd(cp + 1, cy);
    atomicAdd(cp + 2, cz); atomicAdd(cp + 3, cw);
  }
}

// ---- row sums of D and T -> inv-sqrt degree directly ----
__global__ __launch_bounds__(256) void rowinv2_k(const float* __restrict__ D, const float* __restrict__ T,
                                                 float* __restrict__ dd, float* __restrict__ tt){
  const float* A = blockIdx.y ? T : D;
  float* out = blockIdx.y ? tt : dd;
  long row = blockIdx.x;
  const float* p = A + row * ND;
  float s = 0.f;
  for (int c = threadIdx.x * 4; c < ND; c += 1024){
    float4 v = *(const float4*)(p + c);
    s += v.x + v.y + v.z + v.w;
  }
  #pragma unroll
  for (int o = 32; o > 0; o >>= 1) s += __shfl_down(s, o, 64);
  __shared__ float ws[4];
  if ((threadIdx.x & 63) == 0) ws[threadIdx.x >> 6] = s;
  __syncthreads();
  if (threadIdx.x == 0){
    float t = ws[0] + ws[1] + ws[2] + ws[3];
    out[row] = rsqrtf(t == 0.f ? 1.f : t);
  }
}

__global__ __launch_bounds__(256) void invsqrt2_k(const float* __restrict__ rsum, const float* __restrict__ csum,
                                                  float* __restrict__ dt, float* __restrict__ td){
  int i = blockIdx.x * 256 + threadIdx.x;
  if (i < ND){ float v = rsum[i]; dt[i] = rsqrtf(v == 0.f ? 1.f : v); }
  else if (i < ND + NT){ float v = csum[i - ND]; td[i - ND] = rsqrtf(v == 0.f ? 1.f : v); }
}

// ---- link histogram ----
__global__ __launch_bounds__(256) void hist_k(const int* __restrict__ PI, const int* __restrict__ NI,
                                              int* __restrict__ hd, int* __restrict__ ht){
  int id = blockIdx.x * 256 + threadIdx.x;
  if (id >= NLINK) return;
  const int* ip = (id < NPOS) ? (PI + 2 * (long)id) : (NI + 2 * (long)(id - NPOS));
  atomicAdd(&hd[ip[0]], 1);
  atomicAdd(&ht[ip[1]], 1);
}

// ---- exclusive scan of both histograms (single block) ----
__global__ __launch_bounds__(256) void scan_k(const int* __restrict__ h0, const int* __restrict__ h1,
                                              int* __restrict__ o0, int* __restrict__ o1,
                                              int* __restrict__ c0, int* __restrict__ c1){
  __shared__ int sh[256];
  for (int m = 0; m < 2; ++m){
    const int* h = m ? h1 : h0;
    int* o = m ? o1 : o0;
    int* cu = m ? c1 : c0;
    int base = threadIdx.x * 24;
    int loc[24]; int s = 0;
    #pragma unroll
    for (int r = 0; r < 24; ++r){
      loc[r] = s;
      int idx = base + r;
      s += (idx < ND) ? h[idx] : 0;
    }
    sh[threadIdx.x] = s;
    __syncthreads();
    int v = s;
    for (int d = 1; d < 256; d <<= 1){
      int t = (threadIdx.x >= d) ? sh[threadIdx.x - d] : 0;
      __syncthreads();
      v += t; sh[threadIdx.x] = v;
      __syncthreads();
    }
    int prefix = v - s;   // exclusive prefix of this thread's chunk
    #pragma unroll
    for (int r = 0; r < 24; ++r){
      int idx = base + r;
      if (idx < ND){ o[idx] = prefix + loc[r]; cu[idx] = prefix + loc[r]; }
    }
    __syncthreads();
  }
}

// ---- fill CSR buckets: coef = sigmoid(profile . W_pro) * dt_i * td_j * R[i][j] ----
__global__ __launch_bounds__(256) void fill_k(const int* __restrict__ PI, const int* __restrict__ NI,
    const float* __restrict__ PP, const float* __restrict__ NP, const float* __restrict__ WP,
    const float* __restrict__ dt, const float* __restrict__ td, const float* __restrict__ R,
    int* __restrict__ cur_d, int* __restrict__ cur_t,
    int* __restrict__ jd, float* __restrict__ cd, int* __restrict__ jt, float* __restrict__ ct){
  int id = blockIdx.x * 256 + threadIdx.x;
  if (id >= NLINK) return;
  const int* ip = (id < NPOS) ? (PI + 2 * (long)id) : (NI + 2 * (long)(id - NPOS));
  int i = ip[0], j = ip[1];
  const float* p = (id < NPOS) ? (PP + 16 * (long)id) : (NP + 16 * (long)(id - NPOS));
  float s = 0.f;
  #pragma unroll
  for (int q = 0; q < 4; ++q){
    float4 a = *(const float4*)(p + 4 * q);
    float4 w = *(const float4*)(WP + 4 * q);
    s += a.x * w.x + a.y * w.y + a.z * w.z + a.w * w.w;
  }
  float sig = 1.f / (1.f + __expf(-s));
  float coef = sig * dt[i] * td[j] * R[(long)i * NT + j];
  int ed = atomicAdd(&cur_d[i], 1); jd[ed] = j; cd[ed] = coef;
  int et = atomicAdd(&cur_t[j], 1); jt[et] = i; ct[et] = coef;
}

// ---- gather: one wave per destination row, 2 feats/lane, write relu'd f32 ----
__global__ __launch_bounds__(256) void gather_k(
    const int* __restrict__ off_d, const int* __restrict__ h_d, const int* __restrict__ jd,
    const float* __restrict__ cd, const float* __restrict__ Ht, float* __restrict__ accdt,
    const int* __restrict__ off_t, const int* __restrict__ h_t, const int* __restrict__ jt,
    const float* __restrict__ ct, const float* __restrict__ Hd, float* __restrict__ acctd){
  const int* off = blockIdx.y ? off_t : off_d;
  const int* hh  = blockIdx.y ? h_t  : h_d;
  const int* js  = blockIdx.y ? jt   : jd;
  const float* cs= blockIdx.y ? ct   : cd;
  const float* H = blockIdx.y ? Hd   : Ht;
  float* acc     = blockIdx.y ? acctd : accdt;
  int row = blockIdx.x * 4 + (threadIdx.x >> 6);
  int lane = threadIdx.x & 63, f = lane * 2;
  int e0 = off[row], n = hh[row];
  float ax = 0.f, ay = 0.f;
  for (int e = e0; e < e0 + n; ++e){
    int j = js[e]; float c = cs[e];
    const float* hp = H + (long)j * 128 + f;
    ax += c * hp[0]; ay += c * hp[1];
  }
  float* out = acc + (long)row * 128 + f;
  out[0] = fmaxf(ax, 0.f); out[1] = fmaxf(ay, 0.f);
}

// ---- Bt[n][k] = bf16(scale[k] * H[k][n]), zero-padded to Kpad ----
__global__ __launch_bounds__(256) void transpose_scale_k(const float* __restrict__ H,
    const float* __restrict__ scale, u16* __restrict__ Bt, int K, int Kpad){
  __shared__ u16 tile[32][33];
  int k0 = blockIdx.x * 32, n0 = blockIdx.y * 32;
  int tr = threadIdx.x >> 5, tc = threadIdx.x & 31;
  #pragma unroll
  for (int i = 0; i < 4; ++i){
    int k = k0 + tr + i * 8;
    float v = 0.f;
    if (k < K){
      v = H[(long)k * 128 + n0 + tc];
      if (scale) v *= scale[k];
    }
    tile[tr + i * 8][tc] = f2bf(v);
  }
  __syncthreads();
  #pragma unroll
  for (int i = 0; i < 4; ++i){
    int n = n0 + tr + i * 8;
    int k = k0 + tc;
    Bt[(long)n * Kpad + k] = tile[tc][tr + i * 8];
  }
}

// ---- GEMM split-K (plain f32 A): partial sums atomically accumulated into C (f32) ----
// grid: (M/64, 8, 2). C zeroed before launch; scale_relu_k applies relu+scale after.
#define KSPLIT 768
__global__ __launch_bounds__(256) void gemm_plain_k(
    const float* __restrict__ A0, const float* __restrict__ A1,
    const u16* __restrict__ B0, const u16* __restrict__ B1,
    float* __restrict__ C0, float* __restrict__ C1,
    int M, int K, int Kpad){
  const float* A  = blockIdx.z ? A1 : A0;
  const u16* Bt   = blockIdx.z ? B1 : B0;
  float* C        = blockIdx.z ? C1 : C0;

  __shared__ __align__(16) u16 Bs[128][40];
  const int tid = threadIdx.x;
  const int wave = tid >> 6, lane = tid & 63;
  const int quad = lane >> 4, l16 = lane & 15;
  const int row0 = blockIdx.x * 64 + wave * 16;
  const int arow = row0 + l16;

  const int kbeg = blockIdx.y * KSPLIT;
  const int kend = min(kbeg + KSPLIT, K);

  f32x4 acc[8] = {};

  for (int k0 = kbeg; k0 < kend; k0 += 32){
    for (int c = tid; c < 512; c += 256){
      int n = c >> 2, q = c & 3;
      *(uint4*)&Bs[n][q * 8] = *(const uint4*)(Bt + (long)n * Kpad + k0 + q * 8);
    }
    __syncthreads();

    int ka = k0 + quad * 8;
    s16x8 af = {};
    if (arow < M && ka < K){
      const float* ap = A + (long)arow * (long)K + ka;
      float4 a0 = *(const float4*)ap, a1 = *(const float4*)(ap + 4);
      af[0] = (short)f2bf(a0.x); af[1] = (short)f2bf(a0.y);
      af[2] = (short)f2bf(a0.z); af[3] = (short)f2bf(a0.w);
      af[4] = (short)f2bf(a1.x); af[5] = (short)f2bf(a1.y);
      af[6] = (short)f2bf(a1.z); af[7] = (short)f2bf(a1.w);
    }
    #pragma unroll
    for (int t = 0; t < 8; ++t){
      s16x8 bf = *(const s16x8*)&Bs[t * 16 + l16][quad * 8];
      acc[t] = __builtin_amdgcn_mfma_f32_16x16x32_bf16(af, bf, acc[t], 0, 0, 0);
    }
    __syncthreads();
  }

  #pragma unroll
  for (int t = 0; t < 8; ++t){
    #pragma unroll
    for (int r = 0; r < 4; ++r){
      int row = row0 + quad * 4 + r;
      if (row < M)
        atomicAdd(&C[(long)row * 128 + t * 16 + l16], acc[t][r]);
    }
  }
}

// ---- epilogue: C = relu(rs[row] * C), in place, float4 per thread ----
__global__ __launch_bounds__(256) void scale_relu_k(float* __restrict__ C0, float* __restrict__ C1,
    const float* __restrict__ r0, const float* __restrict__ r1){
  float* C = blockIdx.y ? C1 : C0;
  const float* rs = blockIdx.y ? r1 : r0;
  int i = blockIdx.x * 256 + threadIdx.x;   // float4 index, 6000*32 = 192000 total
  if (i >= ND * 32) return;
  int row = i >> 5;
  float s = rs[row];
  float4 v = ((float4*)C)[i];
  v.x = fmaxf(v.x * s, 0.f); v.y = fmaxf(v.y * s, 0.f);
  v.z = fmaxf(v.z * s, 0.f); v.w = fmaxf(v.w * s, 0.f);
  ((float4*)C)[i] = v;
}

// ---- GEMM (concat A = [Xa | Xb | Xc], each Mx128 f32): C = relu(A @ B), K=384 ----
__global__ __launch_bounds__(256) void gemm_cat_k(
    const float* __restrict__ Xa0, const float* __restrict__ Xb0, const float* __restrict__ Xc0,
    const float* __restrict__ Xa1, const float* __restrict__ Xb1, const float* __restrict__ Xc1,
    const u16* __restrict__ B0, const u16* __restrict__ B1,
    float* __restrict__ C0, float* __restrict__ C1, int M){
  const float* Xa = blockIdx.y ? Xa1 : Xa0;
  const float* Xb = blockIdx.y ? Xb1 : Xb0;
  const float* Xc = blockIdx.y ? Xc1 : Xc0;
  const u16* Bt   = blockIdx.y ? B1 : B0;
  float* C        = blockIdx.y ? C1 : C0;

  __shared__ __align__(16) u16 Bs[128][40];
  const int tid = threadIdx.x;
  const int wave = tid >> 6, lane = tid & 63;
  const int quad = lane >> 4, l16 = lane & 15;
  const int row0 = blockIdx.x * 64 + wave * 16;
  const int arow = row0 + l16;

  f32x4 acc[8] = {};

  for (int k0 = 0; k0 < 384; k0 += 32){
    for (int c = tid; c < 512; c += 256){
      int n = c >> 2, q = c & 3;
      *(uint4*)&Bs[n][q * 8] = *(const uint4*)(Bt + (long)n * 384 + k0 + q * 8);
    }
    __syncthreads();

    int ka = k0 + quad * 8;
    int seg = ka >> 7, kk = ka & 127;
    const float* base = (seg == 0) ? Xa : ((seg == 1) ? Xb : Xc);
    s16x8 af = {};
    if (arow < M){
      const float* ap = base + (long)arow * 128 + kk;
      float4 a0 = *(const float4*)ap, a1 = *(const float4*)(ap + 4);
      af[0] = (short)f2bf(a0.x); af[1] = (short)f2bf(a0.y);
      af[2] = (short)f2bf(a0.z); af[3] = (short)f2bf(a0.w);
      af[4] = (short)f2bf(a1.x); af[5] = (short)f2bf(a1.y);
      af[6] = (short)f2bf(a1.z); af[7] = (short)f2bf(a1.w);
    }
    #pragma unroll
    for (int t = 0; t < 8; ++t){
      s16x8 bf = *(const s16x8*)&Bs[t * 16 + l16][quad * 8];
      acc[t] = __builtin_amdgcn_mfma_f32_16x16x32_bf16(af, bf, acc[t], 0, 0, 0);
    }
    __syncthreads();
  }

  #pragma unroll
  for (int t = 0; t < 8; ++t){
    #pragma unroll
    for (int r = 0; r < 4; ++r){
      int row = row0 + quad * 4 + r;
      if (row < M)
        C[(long)row * 128 + t * 16 + l16] = fmaxf(acc[t][r], 0.f);
    }
  }
}

extern "C" void kernel_launch(void* const* d_in, const int* in_sizes, int n_in,
                              void* d_out, int out_size, void* d_ws, size_t ws_size,
                              hipStream_t stream){
  const float* R  = (const float*)d_in[0];
  const float* D  = (const float*)d_in[1];
  const float* T  = (const float*)d_in[2];
  const float* Hd = (const float*)d_in[3];
  const float* Ht = (const float*)d_in[4];
  const float* PP = (const float*)d_in[5];
  const float* NP = (const float*)d_in[6];
  const int*   PI = (const int*)d_in[7];
  const int*   NI = (const int*)d_in[8];
  const float* WP = (const float*)d_in[9];
  const float* WD = (const float*)d_in[10];
  const float* WT = (const float*)d_in[11];

  char* ws = (char*)d_ws;
  float* rsum  = (float*)(ws + 0);
  float* csum  = (float*)(ws + 24000);
  int* hist_d  = (int*)(ws + 48000);
  int* hist_t  = (int*)(ws + 72000);
  int* off_d   = (int*)(ws + 96000);
  int* off_t   = (int*)(ws + 120000);
  int* cur_d   = (int*)(ws + 144000);
  int* cur_t   = (int*)(ws + 168000);
  float* dt    = (float*)(ws + 192000);
  float* td    = (float*)(ws + 216000);
  float* dd    = (float*)(ws + 240000);
  float* tt    = (float*)(ws + 264000);
  int*   jd    = (int*)(ws + 288000);
  float* cd    = (float*)(ws + 1088000);
  int*   jt    = (int*)(ws + 1888000);
  float* ct    = (float*)(ws + 2688000);
  float* accdt = (float*)(ws + 3488000);
  float* acctd = (float*)(ws + 6560000);
  float* Hdd   = (float*)(ws + 9632000);
  float* Htt   = (float*)(ws + 12704000);
  u16*   Btd   = (u16*)(ws + 15776000);
  u16*   Btt   = (u16*)(ws + 17316096);
  u16*   Wtd   = (u16*)(ws + 18856192);
  u16*   Wtt   = (u16*)(ws + 18954496);
  // total 19052800 bytes

  float* outd = (float*)d_out;
  float* outt = outd + (long)ND * 128;

  hipMemsetAsync(d_ws, 0, 96000, stream);            // rsum, csum, hist_d, hist_t
  hipMemsetAsync(ws + 9632000, 0, 6144000, stream);  // Hdd, Htt (split-K accumulators)

  rc_sums_k<<<dim3(6, 200), 256, 0, stream>>>(R, rsum, csum);
  rowinv2_k<<<dim3(ND, 2), 256, 0, stream>>>(D, T, dd, tt);
  invsqrt2_k<<<47, 256, 0, stream>>>(rsum, csum, dt, td);

  hist_k<<<782, 256, 0, stream>>>(PI, NI, hist_d, hist_t);
  scan_k<<<1, 256, 0, stream>>>(hist_d, hist_t, off_d, off_t, cur_d, cur_t);
  fill_k<<<782, 256, 0, stream>>>(PI, NI, PP, NP, WP, dt, td, R, cur_d, cur_t, jd, cd, jt, ct);
  gather_k<<<dim3(1500, 2), 256, 0, stream>>>(off_d, hist_d, jd, cd, Ht, accdt,
                                              off_t, hist_t, jt, ct, Hd, acctd);

  transpose_scale_k<<<dim3(188, 4), 256, 0, stream>>>(Hd, dd, Btd, ND, KPAD);
  transpose_scale_k<<<dim3(188, 4), 256, 0, stream>>>(Ht, tt, Btt, NT, KPAD);
  transpose_scale_k<<<dim3(12, 4), 256, 0, stream>>>(WD, nullptr, Wtd, 384, 384);
  transpose_scale_k<<<dim3(12, 4), 256, 0, stream>>>(WT, nullptr, Wtt, 384, 384);

  gemm_plain_k<<<dim3(94, 8, 2), 256, 0, stream>>>(D, T, Btd, Btt, Hdd, Htt, ND, ND, KPAD);
  scale_relu_k<<<dim3(750, 2), 256, 0, stream>>>(Hdd, Htt, dd, tt);
  gemm_cat_k<<<dim3(94, 2), 256, 0, stream>>>(Hd, accdt, Hdd, Ht, acctd, Htt,
                                              Wtd, Wtt, outd, outt, ND);
}